// Round 8
// baseline (80.716 us; speedup 1.0000x reference)
//
#include <hip/hip_runtime.h>

#define MAXT 100000.0f

constexpr int B    = 64;
constexpr int IN   = 1024;
constexpr int N    = 1025;   // IN + bias column
constexpr int OUTS = 512;
constexpr int NSEG = 16;     // segment-waves per block (1024 threads)
constexpr int SEGL = 64;     // uniform segment length; i=1024 is seg-15 tail
constexpr unsigned KEYMASK = 0xFFFFFC00u;  // top 22 value bits | 10-bit index
constexpr unsigned BIASKEY = 0x3F8003FFu;  // key upper bound for bias rank

struct alignas(8) Pair { unsigned off; unsigned x; };

// ---------------- Fused: per-row sort + gathered-weight scan, 2 j/thread ----
// grid = (B, 4) = 256 blocks -> one block-round on 256 CUs. Each block sorts
// row b (4-way redundant across j-chunks; wall cost equals a standalone
// sort), then scans 128 j columns, 2 per thread via float2 loads.
// R7 post-mortem model: kernel ~17 us = sort ~3.5 + pass1 ~3 (L2-gather
// latency) + pass2 ~6 (issue) + reductions/slack ~1.5; harness fixed floor
// ~61-63 us (268 MB ws re-poison @83% HBM + restores + dispatch slots).
// This round: pn-carry kills the per-iter xn LDS read; xsh deleted; pass1
// unroll 16 for deeper memory-level parallelism.
__global__ __launch_bounds__(1024, 4) void snn_fused(
    const float* __restrict__ layer_in,
    const float* __restrict__ weight,
    const float* __restrict__ delay,
    float* __restrict__ out) {
  __shared__ unsigned ksh[IN];
  __shared__ float vsh[IN];
  __shared__ __align__(16) Pair ps[N];   // sorted {w byte-offset, x bits}
  __shared__ float4 red4[NSEG][64];      // pass-1 partials / final reduction

  const int b    = blockIdx.x;
  const int jc   = blockIdx.y;
  const int lane = threadIdx.x;        // j pair
  const int seg  = threadIdx.y;        // i segment
  const int tid  = seg * 64 + lane;
  const unsigned jadd = (unsigned)((jc * 128 + lane * 2) * 4);  // byte offset

  // ---- Phase A: scaled input + 1-elem/thread bitonic argsort ----
  {
    float d = delay[tid];
    float v = layer_in[b * IN + tid] * expf(d > 0.0f ? d : 0.0f);
    vsh[tid] = v;                                 // exact x, gathered at end
    unsigned k = (__float_as_uint(v) & KEYMASK) | (unsigned)tid;

#pragma unroll
    for (int kk = 2; kk <= IN; kk <<= 1) {
#pragma unroll
      for (int jj = kk >> 1; jj > 0; jj >>= 1) {
        unsigned other;
        if (jj >= 64) {              // cross-wave exchange via LDS
          __syncthreads();           // WAR vs previous stage's reads
          ksh[tid] = k;
          __syncthreads();
          other = ksh[tid ^ jj];
        } else {                     // in-wave exchange, barrier-free
          other = __shfl_xor(k, jj, 64);
        }
        bool up    = ((tid & kk) == 0);
        bool lower = ((tid & jj) == 0);
        unsigned mn = k < other ? k : other;
        unsigned mx = k < other ? other : k;
        k = (up == lower) ? mn : mx;
      }
    }

    // bias (x=1.0, idx=IN) rank = #elements sorting before it (stable order)
    int r = __syncthreads_count((k <= BIASKEY) ? 1 : 0);

    int idx = (int)(k & 1023u);
    float x = vsh[idx];
    int pos = tid + (tid >= r);
    Pair pr; pr.off = (unsigned)(idx * OUTS * 4); pr.x = __float_as_uint(x);
    ps[pos] = pr;
    if (tid == 0) {
      Pair bias; bias.off = (unsigned)(IN * OUTS * 4); bias.x = __float_as_uint(1.0f);
      ps[r] = bias;
    }
    __syncthreads();
  }

  // ---- Phase B: segmented scan, first-valid latch, 2 j per thread ----
  const char* wbase = (const char*)weight;
  const int is = seg * SEGL;

  // Pass 1: per-segment partial sums of (w, w*x) for both j.
  float pw0 = 0.0f, pw1 = 0.0f, px0 = 0.0f, px1 = 0.0f;
#pragma unroll 16
  for (int u = 0; u < SEGL; ++u) {
    Pair p = ps[is + u];
    float2 w = *(const float2*)(wbase + (p.off + jadd));
    float xv = __uint_as_float(p.x);
    pw0 += w.x; pw1 += w.y;
    px0 = fmaf(w.x, xv, px0);
    px1 = fmaf(w.y, xv, px1);
  }
  red4[seg][lane] = make_float4(pw0, pw1, px0, px1);
  __syncthreads();

  // Exclusive prefix over segments; wc holds w_cum - 1.
  float wc0 = -1.0f, wc1 = -1.0f, wi0 = 0.0f, wi1 = 0.0f;
  for (int s = 0; s < seg; ++s) {
    float4 t = red4[s][lane];
    wc0 += t.x; wc1 += t.y; wi0 += t.z; wi1 += t.w;
  }

  // Pass 2: latch first valid candidate per j (bd<0 encodes "not found").
  // Valid at step i <=> min3(wc, wi - xi*wc, xn*wc - wi) >= 0; xs sorted =>
  // the first valid candidate IS the filtered min. pn-carry: one b64
  // broadcast read per iter supplies both next w-offset and xn.
  float bn0 = MAXT, bd0 = -1.0f, bn1 = MAXT, bd1 = -1.0f;
  Pair p = ps[is];
  float xi = __uint_as_float(p.x);
#pragma unroll 8
  for (int u = 0; u < SEGL; ++u) {
    Pair pn = ps[is + u + 1];               // seg15,u=63 -> ps[1024], valid
    float2 w = *(const float2*)(wbase + (p.off + jadd));
    float xn = __uint_as_float(pn.x);
    wc0 += w.x;
    wi0 = fmaf(w.x, xi, wi0);
    wc1 += w.y;
    wi1 = fmaf(w.y, xi, wi1);
    float m0 = fminf(fminf(wc0, fmaf(-xi, wc0, wi0)), fmaf(xn, wc0, -wi0));
    float m1 = fminf(fminf(wc1, fmaf(-xi, wc1, wi1)), fmaf(xn, wc1, -wi1));
    bool f0 = (bd0 < 0.0f) & (m0 >= 0.0f);
    bool f1 = (bd1 < 0.0f) & (m1 >= 0.0f);
    bn0 = f0 ? wi0 : bn0;
    bd0 = f0 ? wc0 : bd0;
    bn1 = f1 ? wi1 : bn1;
    bd1 = f1 ? wc1 : bd1;
    p = pn; xi = xn;
  }
  if (seg == NSEG - 1) {            // tail i = 1024: p == ps[1024], xn = MAXT
    float2 w = *(const float2*)(wbase + (p.off + jadd));
    wc0 += w.x;
    wi0 = fmaf(w.x, xi, wi0);
    wc1 += w.y;
    wi1 = fmaf(w.y, xi, wi1);
    float m0 = fminf(fminf(wc0, fmaf(-xi, wc0, wi0)), fmaf(MAXT, wc0, -wi0));
    float m1 = fminf(fminf(wc1, fmaf(-xi, wc1, wi1)), fmaf(MAXT, wc1, -wi1));
    bool f0 = (bd0 < 0.0f) & (m0 >= 0.0f);
    bool f1 = (bd1 < 0.0f) & (m1 >= 0.0f);
    bn0 = f0 ? wi0 : bn0;
    bd0 = f0 ? wc0 : bd0;
    bn1 = f1 ? wi1 : bn1;
    bd1 = f1 ? wc1 : bd1;
  }
  float best0 = (bd0 < 0.0f) ? MAXT : bn0 * __builtin_amdgcn_rcpf(fmaxf(bd0, 1e-10f));
  float best1 = (bd1 < 0.0f) ? MAXT : bn1 * __builtin_amdgcn_rcpf(fmaxf(bd1, 1e-10f));

  __syncthreads();                           // all prefix reads of red4 done
  red4[seg][lane] = make_float4(best0, best1, 0.0f, 0.0f);
  __syncthreads();
  if (seg == 0) {
    float4 m = red4[0][lane];
#pragma unroll
    for (int s = 1; s < NSEG; ++s) {
      float4 t = red4[s][lane];
      m.x = fminf(m.x, t.x);
      m.y = fminf(m.y, t.y);
    }
    *(float2*)(&out[b * OUTS + jc * 128 + lane * 2]) = make_float2(m.x, m.y);
  }
}

extern "C" void kernel_launch(void* const* d_in, const int* in_sizes, int n_in,
                              void* d_out, int out_size, void* d_ws, size_t ws_size,
                              hipStream_t stream) {
  const float* layer_in = (const float*)d_in[0];
  const float* weight   = (const float*)d_in[1];
  const float* delay    = (const float*)d_in[2];
  float* out = (float*)d_out;
  (void)d_ws; (void)ws_size;

  snn_fused<<<dim3(B, OUTS / 128), dim3(64, NSEG), 0, stream>>>(
      layer_in, weight, delay, out);
}

// Round 9
// 80.686 us; speedup vs baseline: 1.0004x; 1.0004x over previous
//
#include <hip/hip_runtime.h>

#define MAXT 100000.0f

constexpr int B    = 64;
constexpr int IN   = 1024;
constexpr int N    = 1025;   // IN + bias column
constexpr int OUTS = 512;
constexpr int NSEG = 16;     // segment-waves per block (1024 threads)
constexpr int SEGL = 64;     // uniform segment length; i=1024 is seg-15 tail
constexpr unsigned KEYMASK = 0xFFFFFC00u;  // top 22 value bits | 10-bit index
constexpr unsigned BIASKEY = 0x3F8003FFu;  // key upper bound for bias rank

struct alignas(8) Pair { unsigned off; unsigned x; };

// ---------------- Fused: per-row sort + gathered-weight scan, 2 j/thread ----
// grid = (B, 4) = 256 blocks -> one block-round on 256 CUs. Each block sorts
// row b (4-way redundant across j-chunks; wall cost equals a standalone
// sort), then scans 128 j columns, 2 per thread via float2 loads.
// FINAL (R9 = revert to R7, the best measured variant at 79.89 us):
//   R8's pn-carry/xsh-deletion/unroll-16 bundle regressed +0.8 us — the
//   carried Pair read joined the loop-carried chain, while xsh's independent
//   ds_read_b32 could issue ahead. Keep the independent xsh stream.
// Cost model: kernel ~17 us = sort ~3.5 (20 barrier-serialized LDS stages,
// shape-irreducible) + pass1 ~3 (L2-gather latency) + pass2 ~6 (issue:
// ~26 VALU x 64 iters x 2 cy x 4 waves/SIMD) + reductions/slack ~1.5.
// Harness fixed floor ~61-63 us (268 MB ws re-poison @83% HBM = 40.3 us,
// + out-fill + input restores + dispatch slots) — all top-5 dispatches are
// fillBufferAligned every round; nothing kernel-side can touch it.
__global__ __launch_bounds__(1024, 4) void snn_fused(
    const float* __restrict__ layer_in,
    const float* __restrict__ weight,
    const float* __restrict__ delay,
    float* __restrict__ out) {
  __shared__ unsigned ksh[IN];
  __shared__ float vsh[IN];
  __shared__ __align__(16) Pair ps[N + 1];
  __shared__ float xsh[N + 1];
  __shared__ float4 red4[NSEG][64];    // pass-1 partials / final reduction

  const int b    = blockIdx.x;
  const int jc   = blockIdx.y;
  const int lane = threadIdx.x;        // j pair
  const int seg  = threadIdx.y;        // i segment
  const int tid  = seg * 64 + lane;
  const unsigned jadd = (unsigned)((jc * 128 + lane * 2) * 4);  // byte offset

  // ---- Phase A: scaled input + 1-elem/thread bitonic argsort ----
  {
    float d = delay[tid];
    float v = layer_in[b * IN + tid] * expf(d > 0.0f ? d : 0.0f);
    vsh[tid] = v;                                 // exact x, gathered at end
    unsigned k = (__float_as_uint(v) & KEYMASK) | (unsigned)tid;

#pragma unroll
    for (int kk = 2; kk <= IN; kk <<= 1) {
#pragma unroll
      for (int jj = kk >> 1; jj > 0; jj >>= 1) {
        unsigned other;
        if (jj >= 64) {              // cross-wave exchange via LDS
          __syncthreads();           // WAR vs previous stage's reads
          ksh[tid] = k;
          __syncthreads();
          other = ksh[tid ^ jj];
        } else {                     // in-wave exchange, barrier-free
          other = __shfl_xor(k, jj, 64);
        }
        bool up    = ((tid & kk) == 0);
        bool lower = ((tid & jj) == 0);
        unsigned mn = k < other ? k : other;
        unsigned mx = k < other ? other : k;
        k = (up == lower) ? mn : mx;
      }
    }

    // bias (x=1.0, idx=IN) rank = #elements sorting before it (stable order)
    int r = __syncthreads_count((k <= BIASKEY) ? 1 : 0);

    int idx = (int)(k & 1023u);
    float x = vsh[idx];
    int pos = tid + (tid >= r);
    Pair pr; pr.off = (unsigned)(idx * OUTS * 4); pr.x = __float_as_uint(x);
    ps[pos] = pr;
    xsh[pos] = x;
    if (tid == 0) {
      Pair bias; bias.off = (unsigned)(IN * OUTS * 4); bias.x = __float_as_uint(1.0f);
      ps[r] = bias; xsh[r] = 1.0f;
      Pair sent; sent.off = 0u; sent.x = __float_as_uint(MAXT);
      ps[N] = sent; xsh[N] = MAXT;
    }
    __syncthreads();
  }

  // ---- Phase B: segmented scan, first-valid latch, 2 j per thread ----
  const char* wbase = (const char*)weight;
  const int is = seg * SEGL;

  // Pass 1: per-segment partial sums of (w, w*x) for both j.
  float pw0 = 0.0f, pw1 = 0.0f, px0 = 0.0f, px1 = 0.0f;
#pragma unroll 8
  for (int u = 0; u < SEGL; ++u) {
    Pair p = ps[is + u];
    float2 w = *(const float2*)(wbase + (p.off + jadd));
    float xv = __uint_as_float(p.x);
    pw0 += w.x; pw1 += w.y;
    px0 = fmaf(w.x, xv, px0);
    px1 = fmaf(w.y, xv, px1);
  }
  red4[seg][lane] = make_float4(pw0, pw1, px0, px1);
  __syncthreads();

  // Exclusive prefix over segments; wc holds w_cum - 1.
  float wc0 = -1.0f, wc1 = -1.0f, wi0 = 0.0f, wi1 = 0.0f;
  for (int s = 0; s < seg; ++s) {
    float4 t = red4[s][lane];
    wc0 += t.x; wc1 += t.y; wi0 += t.z; wi1 += t.w;
  }

  // Pass 2: latch first valid candidate per j (bd<0 encodes "not found").
  // Valid at step i <=> min3(wc, wi - xi*wc, xn*wc - wi) >= 0; xs sorted =>
  // the first valid candidate IS the filtered min.
  float bn0 = MAXT, bd0 = -1.0f, bn1 = MAXT, bd1 = -1.0f;
  float xi = xsh[is];
#pragma unroll 8
  for (int u = 0; u < SEGL; ++u) {
    Pair p = ps[is + u];
    float2 w = *(const float2*)(wbase + (p.off + jadd));
    float xn = xsh[is + u + 1];
    wc0 += w.x;
    wi0 = fmaf(w.x, xi, wi0);
    wc1 += w.y;
    wi1 = fmaf(w.y, xi, wi1);
    float m0 = fminf(fminf(wc0, fmaf(-xi, wc0, wi0)), fmaf(xn, wc0, -wi0));
    float m1 = fminf(fminf(wc1, fmaf(-xi, wc1, wi1)), fmaf(xn, wc1, -wi1));
    bool f0 = (bd0 < 0.0f) & (m0 >= 0.0f);
    bool f1 = (bd1 < 0.0f) & (m1 >= 0.0f);
    bn0 = f0 ? wi0 : bn0;
    bd0 = f0 ? wc0 : bd0;
    bn1 = f1 ? wi1 : bn1;
    bd1 = f1 ? wc1 : bd1;
    xi = xn;
  }
  if (seg == NSEG - 1) {                     // tail element i = 1024
    Pair p = ps[N - 1];
    float2 w = *(const float2*)(wbase + (p.off + jadd));
    float xn = xsh[N];                       // MAXT sentinel
    wc0 += w.x;
    wi0 = fmaf(w.x, xi, wi0);
    wc1 += w.y;
    wi1 = fmaf(w.y, xi, wi1);
    float m0 = fminf(fminf(wc0, fmaf(-xi, wc0, wi0)), fmaf(xn, wc0, -wi0));
    float m1 = fminf(fminf(wc1, fmaf(-xi, wc1, wi1)), fmaf(xn, wc1, -wi1));
    bool f0 = (bd0 < 0.0f) & (m0 >= 0.0f);
    bool f1 = (bd1 < 0.0f) & (m1 >= 0.0f);
    bn0 = f0 ? wi0 : bn0;
    bd0 = f0 ? wc0 : bd0;
    bn1 = f1 ? wi1 : bn1;
    bd1 = f1 ? wc1 : bd1;
  }
  float best0 = (bd0 < 0.0f) ? MAXT : bn0 * __builtin_amdgcn_rcpf(fmaxf(bd0, 1e-10f));
  float best1 = (bd1 < 0.0f) ? MAXT : bn1 * __builtin_amdgcn_rcpf(fmaxf(bd1, 1e-10f));

  __syncthreads();                           // all prefix reads of red4 done
  red4[seg][lane] = make_float4(best0, best1, 0.0f, 0.0f);
  __syncthreads();
  if (seg == 0) {
    float4 m = red4[0][lane];
#pragma unroll
    for (int s = 1; s < NSEG; ++s) {
      float4 t = red4[s][lane];
      m.x = fminf(m.x, t.x);
      m.y = fminf(m.y, t.y);
    }
    *(float2*)(&out[b * OUTS + jc * 128 + lane * 2]) = make_float2(m.x, m.y);
  }
}

extern "C" void kernel_launch(void* const* d_in, const int* in_sizes, int n_in,
                              void* d_out, int out_size, void* d_ws, size_t ws_size,
                              hipStream_t stream) {
  const float* layer_in = (const float*)d_in[0];
  const float* weight   = (const float*)d_in[1];
  const float* delay    = (const float*)d_in[2];
  float* out = (float*)d_out;
  (void)d_ws; (void)ws_size;

  snn_fused<<<dim3(B, OUTS / 128), dim3(64, NSEG), 0, stream>>>(
      layer_in, weight, delay, out);
}